// Round 7
// baseline (330.609 us; speedup 1.0000x reference)
//
#include <hip/hip_runtime.h>
#include <hip/hip_bf16.h>

constexpr int kNN  = 10000;   // nodes
constexpr int kTT  = 12;      // timesteps
constexpr int kFIN = 32;      // input features
constexpr int kHH  = 64;      // hidden
constexpr int kH4  = 256;     // 4*hidden (gates)
constexpr int kOUT = 16;      // output features
constexpr int kNE  = 160000;  // edges

typedef _Float16 half8 __attribute__((ext_vector_type(8)));
typedef _Float16 half4 __attribute__((ext_vector_type(4)));
typedef _Float16 half2t __attribute__((ext_vector_type(2)));
typedef float floatx4 __attribute__((ext_vector_type(4)));

__device__ __forceinline__ float sigf(float x){ return 1.f/(1.f+__expf(-x)); }
__device__ __forceinline__ float tanh_fast(float x){
  float xc = fminf(fmaxf(x,-30.f),30.f);
  float e = __expf(-2.f*xc);
  return (1.f-e)/(1.f+e);
}

// int64-vs-int32 edge_index detection (odd words all zero <=> int64) fused
// with the x fp32 -> fp16 cast (independent elementwise work, saves a launch).
__global__ void k_detect_cast(const int* __restrict__ ei, int* __restrict__ anyf,
                              const float* __restrict__ x, _Float16* __restrict__ xh){
  int a = 0;
  for (int i = blockIdx.x*256 + threadIdx.x; i < kNE; i += gridDim.x*256)
    a |= ei[2*i+1];
  unsigned long long m = __ballot(a != 0);
  if ((threadIdx.x & 63) == 0 && m) atomicOr(anyf, 1);
  const int NV = kNN*kTT*kFIN/4;
  for (int i = blockIdx.x*256 + threadIdx.x; i < NV; i += gridDim.x*256){
    float4 v = *(const float4*)&x[4*i];
    half4 h;
    h[0]=(_Float16)v.x; h[1]=(_Float16)v.y; h[2]=(_Float16)v.z; h[3]=(_Float16)v.w;
    *(half4*)&xh[4*i] = h;
  }
}

__global__ void k_deg(const int* __restrict__ ei, const int* __restrict__ anyf,
                      int* __restrict__ cnt){
  int e = blockIdx.x*256 + threadIdx.x;
  if (e >= kNE) return;
  int c = (anyf[0]==0) ? ei[2*(kNE+e)] : ei[kNE+e];
  atomicAdd(&cnt[c], 1);
}

// Exclusive scan of in-degree (single block, shuffle-based partial scan)
// + dis = rsqrt(deg+selfloop)
__global__ void k_scan(const int* __restrict__ cnt, int* __restrict__ offs,
                       float* __restrict__ dis){
  __shared__ int wsum[4];
  int tid = threadIdx.x;
  const int CH = (kNN + 255)/256;
  int lo = tid*CH, hi = min(lo+CH, kNN);
  int s = 0;
  for (int i = lo; i < hi; ++i) s += cnt[i];
  int orig = s;
  int lane = tid & 63, wv = tid >> 6;
  #pragma unroll
  for (int d = 1; d < 64; d <<= 1){
    int v = __shfl_up(s, d, 64);
    if (lane >= d) s += v;
  }
  if (lane == 63) wsum[wv] = s;
  __syncthreads();
  int add = 0;
  for (int k2 = 0; k2 < wv; ++k2) add += wsum[k2];
  int run = s - orig + add;          // exclusive prefix for this thread's chunk
  for (int i = lo; i < hi; ++i){ offs[i] = run; run += cnt[i]; }
  if (hi == kNN) offs[kNN] = run;
  for (int i = tid; i < kNN; i += 256) dis[i] = rsqrtf((float)(cnt[i]+1));
}

// CSR scatter; packs (src, weight) into one int2 per edge.
__global__ void k_scatter(const int* __restrict__ ei, const int* __restrict__ anyf,
                          const int* __restrict__ offs, int* __restrict__ cur,
                          const float* __restrict__ dis,
                          int2* __restrict__ edat){
  int e = blockIdx.x*256 + threadIdx.x;
  if (e >= kNE) return;
  int f = (anyf[0]==0);
  int r = f ? ei[2*e]         : ei[e];
  int c = f ? ei[2*(kNE+e)]   : ei[kNE+e];
  int p = offs[c] + atomicAdd(&cur[c], 1);
  edat[p] = make_int2(r, __float_as_int(dis[r]*dis[c]));
}

// Pure GCN aggregation (bias/relu folded into the following GEMM since
// A_hat(xW) = (A_hat x)W). F features fp16; t-major in/out for L2 locality.
template<int F>
__global__ __launch_bounds__(256) void k_agg(const _Float16* __restrict__ hin,
                     _Float16* __restrict__ hout,
                     const float* __restrict__ dis,
                     const int* __restrict__ offs, const int2* __restrict__ edat){
  constexpr int LPF = F/2;            // lanes per timestep
  constexpr int TPW = 64/LPF;         // timesteps per wave
  int wid = threadIdx.x >> 6, lane = threadIdx.x & 63;
  int gw = blockIdx.x*4 + wid;        // gw = tq*kNN + n
  int tq = gw / kNN, n = gw - tq*kNN;
  int fp = lane & (LPF-1), tsub = lane / LPF;
  int t = TPW*tq + tsub;
  const _Float16* hb = hin + (size_t)t*kNN*F;
  float d = dis[n], ws = d*d;
  half2t sv = *(const half2t*)&hb[(size_t)n*F + 2*fp];
  float a0 = ws*(float)sv[0], a1 = ws*(float)sv[1];
  int e0 = __builtin_amdgcn_readfirstlane(offs[n]);
  int e1 = __builtin_amdgcn_readfirstlane(offs[n+1]);
  int e = e0;
  for (; e + 8 <= e1; e += 8){
    int2 d8[8];
    #pragma unroll
    for (int u = 0; u < 8; ++u) d8[u] = edat[e+u];
    half2t v[8];
    #pragma unroll
    for (int u = 0; u < 8; ++u) v[u] = *(const half2t*)&hb[(size_t)d8[u].x*F + 2*fp];
    #pragma unroll
    for (int u = 0; u < 8; ++u){
      float wu = __int_as_float(d8[u].y);
      a0 = fmaf(wu, (float)v[u][0], a0);
      a1 = fmaf(wu, (float)v[u][1], a1);
    }
  }
  for (; e < e1; ++e){
    int2 du = edat[e];
    float wu = __int_as_float(du.y);
    half2t vu = *(const half2t*)&hb[(size_t)du.x*F + 2*fp];
    a0 = fmaf(wu, (float)vu[0], a0);
    a1 = fmaf(wu, (float)vu[1], a1);
  }
  half2t o; o[0] = (_Float16)a0; o[1] = (_Float16)a1;
  *(half2t*)&hout[((size_t)t*kNN + n)*F + 2*fp] = o;
}

// Tiled GEMM: out[M,N] = relu(in[M,K] @ W[K,N] + bias), fp16 in/out, fp32 acc.
// Rows m are t-major (m = t*kNN + n). NM: store node-major ((n*T+t)*N).
template<int K, int N, bool NM>
__global__ __launch_bounds__(256) void k_gemm(const _Float16* __restrict__ in,
                      const float* __restrict__ Wg, const float* __restrict__ bias,
                      _Float16* __restrict__ out){
  constexpr int COLG = N/4;
  constexpr int ROWG = 256/COLG;
  constexpr int MR   = 4;
  constexpr int MTILE= ROWG*MR;       // 64
  constexpr int AP   = K + 4;
  __shared__ float Wl[K*N];
  __shared__ float Al[MTILE*AP];
  int tid = threadIdx.x;
  int m0 = blockIdx.x*MTILE;
  for (int idx = tid; idx < MTILE*K/8; idx += 256){
    int r = idx/(K/8), k8 = idx - r*(K/8);
    half8 v = *(const half8*)&in[(size_t)(m0 + r)*K + k8*8];
    float* dst = &Al[r*AP + k8*8];
    #pragma unroll
    for (int j = 0; j < 8; ++j) dst[j] = (float)v[j];
  }
  for (int idx = tid; idx < K*N; idx += 256) Wl[idx] = Wg[idx];
  __syncthreads();
  int cg = tid % COLG, rg = tid / COLG;
  int c0 = cg*4, r0 = rg*MR;
  float acc[MR][4];
  #pragma unroll
  for (int r=0;r<MR;++r){acc[r][0]=0.f;acc[r][1]=0.f;acc[r][2]=0.f;acc[r][3]=0.f;}
  #pragma unroll 2
  for (int k = 0; k < K; k += 4){
    float4 wv[4];
    #pragma unroll
    for (int kk = 0; kk < 4; ++kk) wv[kk] = *(const float4*)&Wl[(k+kk)*N + c0];
    #pragma unroll
    for (int r = 0; r < MR; ++r){
      float4 a4 = *(const float4*)&Al[(r0+r)*AP + k];
      acc[r][0] = fmaf(a4.x, wv[0].x, acc[r][0]);
      acc[r][1] = fmaf(a4.x, wv[0].y, acc[r][1]);
      acc[r][2] = fmaf(a4.x, wv[0].z, acc[r][2]);
      acc[r][3] = fmaf(a4.x, wv[0].w, acc[r][3]);
      acc[r][0] = fmaf(a4.y, wv[1].x, acc[r][0]);
      acc[r][1] = fmaf(a4.y, wv[1].y, acc[r][1]);
      acc[r][2] = fmaf(a4.y, wv[1].z, acc[r][2]);
      acc[r][3] = fmaf(a4.y, wv[1].w, acc[r][3]);
      acc[r][0] = fmaf(a4.z, wv[2].x, acc[r][0]);
      acc[r][1] = fmaf(a4.z, wv[2].y, acc[r][1]);
      acc[r][2] = fmaf(a4.z, wv[2].z, acc[r][2]);
      acc[r][3] = fmaf(a4.z, wv[2].w, acc[r][3]);
      acc[r][0] = fmaf(a4.w, wv[3].x, acc[r][0]);
      acc[r][1] = fmaf(a4.w, wv[3].y, acc[r][1]);
      acc[r][2] = fmaf(a4.w, wv[3].z, acc[r][2]);
      acc[r][3] = fmaf(a4.w, wv[3].w, acc[r][3]);
    }
  }
  float4 bb = *(const float4*)&bias[c0];
  #pragma unroll
  for (int r = 0; r < MR; ++r){
    half4 hv;
    hv[0]=(_Float16)fmaxf(acc[r][0]+bb.x, 0.f);
    hv[1]=(_Float16)fmaxf(acc[r][1]+bb.y, 0.f);
    hv[2]=(_Float16)fmaxf(acc[r][2]+bb.z, 0.f);
    hv[3]=(_Float16)fmaxf(acc[r][3]+bb.w, 0.f);
    int m = m0 + r0 + r;
    size_t oi;
    if (NM){ int t = m/kNN, n = m - t*kNN; oi = ((size_t)n*kTT + t)*N + c0; }
    else    oi = (size_t)m*N + c0;
    *(half4*)&out[oi] = hv;
  }
}

// Fused 2-layer LSTM + FC, NO global memory ops inside the t-loop.
// Key fix vs R4-R6: __syncthreads drains vmcnt(0), so any in-flight global
// prefetch serializes ~900cyc of HBM latency into EVERY stage barrier.
// Here x for the block's 16 nodes (24KB) is staged to LDS once up front;
// the 12-step recurrence touches only LDS (barrier drains are ~120cyc lgkm).
// Block = 4 waves = one 16-node tile; wave w owns cells [16w,16w+16) of BOTH
// layers (gate tiles {w,4+w,8+w,12+w}); all 4 weight matrices live in VGPRs
// (128). h0/h1 exchanged C->A layout via single-buffered LDS tiles: reads
// complete before the barrier (lgkm drain), writes happen after the next
// barrier -> race-free. FC at t=11 by wave 0 (2 MFMAs). Grid 625 blocks.
// MFMA 16x16x32 layouts: A[m=lane&15][k=(lane>>4)*8+j], B^T rows same,
// C/D[row=(lane>>4)*4+r][col=lane&15].
__global__ __launch_bounds__(256) void k_rec3(const _Float16* __restrict__ xin,
                     const float* __restrict__ wih0, const float* __restrict__ whh0,
                     const float* __restrict__ bih0, const float* __restrict__ bhh0,
                     const float* __restrict__ wih1, const float* __restrict__ whh1,
                     const float* __restrict__ bih1, const float* __restrict__ bhh1,
                     const float* __restrict__ fcw, const float* __restrict__ fcb,
                     float* __restrict__ out){
  constexpr int XP  = kTT*kHH + 8;   // 776 halves: b128-aligned, 2-way-bank only
  constexpr int LPH = 72;            // h tile pitch (halves)
  __shared__ _Float16 xl[16*XP];     // 24.25KB staged x
  __shared__ _Float16 h0l[16*LPH];
  __shared__ _Float16 h1l[16*LPH];
  int tid = threadIdx.x, w = tid >> 6, lane = tid & 63;
  int lo = lane & 15, hi4 = lane >> 4;
  int nb = blockIdx.x*16;

  // Stage x: 16 rows x 768 halves, coalesced half8 copies (1536 chunks).
  for (int idx = tid; idx < 16*(kTT*kHH/8); idx += 256){
    int r = idx/(kTT*kHH/8), c8 = idx - r*(kTT*kHH/8);
    *(half8*)&xl[r*XP + c8*8] = *(const half8*)&xin[((size_t)(nb+r)*kTT*kHH) + c8*8];
  }

  // Register-resident weight fragments: tile g4 covers gate rows
  // g4*64 + w*16 + lo of each (256,64) matrix.
  half8 BI0[4][2], BH0[4][2], BI1[4][2], BH1[4][2];
  float bias0[4], bias1[4];
  #pragma unroll
  for (int g4 = 0; g4 < 4; ++g4){
    int row = g4*kHH + w*16 + lo;
    bias0[g4] = bih0[row] + bhh0[row];
    bias1[g4] = bih1[row] + bhh1[row];
    #pragma unroll
    for (int kt = 0; kt < 2; ++kt){
      const float* p0 = wih0 + (size_t)row*kHH + kt*32 + hi4*8;
      const float* q0 = whh0 + (size_t)row*kHH + kt*32 + hi4*8;
      const float* p1 = wih1 + (size_t)row*kHH + kt*32 + hi4*8;
      const float* q1 = whh1 + (size_t)row*kHH + kt*32 + hi4*8;
      half8 a, b, c2, d2;
      #pragma unroll
      for (int j = 0; j < 8; ++j){
        a[j]=(_Float16)p0[j]; b[j]=(_Float16)q0[j];
        c2[j]=(_Float16)p1[j]; d2[j]=(_Float16)q1[j];
      }
      BI0[g4][kt]=a; BH0[g4][kt]=b; BI1[g4][kt]=c2; BH1[g4][kt]=d2;
    }
  }
  half8 FW[2];
  if (w == 0){
    #pragma unroll
    for (int kt = 0; kt < 2; ++kt){
      const float* pf = fcw + (size_t)lo*kHH + kt*32 + hi4*8;
      half8 f;
      #pragma unroll
      for (int j = 0; j < 8; ++j) f[j] = (_Float16)pf[j];
      FW[kt] = f;
    }
  }

  float c0s[4] = {0.f,0.f,0.f,0.f}, c1s[4] = {0.f,0.f,0.f,0.f};
  half8 ah0[2], ah1[2];
  __syncthreads();   // x staging visible

  for (int t = 0; t < kTT; ++t){
    // ---- layer 0: gates = x(t)@Wih0^T + h0(t-1)@Whh0^T ----
    half8 ax0 = *(const half8*)&xl[lo*XP + t*kHH + hi4*8];
    half8 ax1 = *(const half8*)&xl[lo*XP + t*kHH + 32 + hi4*8];
    floatx4 acc[4];
    #pragma unroll
    for (int g4 = 0; g4 < 4; ++g4){
      floatx4 a = {0.f,0.f,0.f,0.f};
      a = __builtin_amdgcn_mfma_f32_16x16x32_f16(ax0, BI0[g4][0], a, 0,0,0);
      a = __builtin_amdgcn_mfma_f32_16x16x32_f16(ax1, BI0[g4][1], a, 0,0,0);
      acc[g4] = a;
    }
    if (t > 0){
      #pragma unroll
      for (int g4 = 0; g4 < 4; ++g4){
        floatx4 a = acc[g4];
        a = __builtin_amdgcn_mfma_f32_16x16x32_f16(ah0[0], BH0[g4][0], a, 0,0,0);
        a = __builtin_amdgcn_mfma_f32_16x16x32_f16(ah0[1], BH0[g4][1], a, 0,0,0);
        acc[g4] = a;
      }
    }
    #pragma unroll
    for (int r = 0; r < 4; ++r){
      float gi = acc[0][r] + bias0[0];
      float gf = acc[1][r] + bias0[1];
      float gg = acc[2][r] + bias0[2];
      float go = acc[3][r] + bias0[3];
      float ii = sigf(gi), ff = sigf(gf), gt = tanh_fast(gg), oo = sigf(go);
      c0s[r] = ff*c0s[r] + ii*gt;
      float hn = oo * tanh_fast(c0s[r]);
      h0l[(hi4*4 + r)*LPH + w*16 + lo] = (_Float16)hn;
    }
    __syncthreads();
    #pragma unroll
    for (int kt = 0; kt < 2; ++kt)
      ah0[kt] = *(const half8*)&h0l[lo*LPH + kt*32 + hi4*8];

    // ---- layer 1: gates = h0(t)@Wih1^T + h1(t-1)@Whh1^T ----
    #pragma unroll
    for (int g4 = 0; g4 < 4; ++g4){
      floatx4 a = {0.f,0.f,0.f,0.f};
      a = __builtin_amdgcn_mfma_f32_16x16x32_f16(ah0[0], BI1[g4][0], a, 0,0,0);
      a = __builtin_amdgcn_mfma_f32_16x16x32_f16(ah0[1], BI1[g4][1], a, 0,0,0);
      acc[g4] = a;
    }
    if (t > 0){
      #pragma unroll
      for (int g4 = 0; g4 < 4; ++g4){
        floatx4 a = acc[g4];
        a = __builtin_amdgcn_mfma_f32_16x16x32_f16(ah1[0], BH1[g4][0], a, 0,0,0);
        a = __builtin_amdgcn_mfma_f32_16x16x32_f16(ah1[1], BH1[g4][1], a, 0,0,0);
        acc[g4] = a;
      }
    }
    #pragma unroll
    for (int r = 0; r < 4; ++r){
      float gi = acc[0][r] + bias1[0];
      float gf = acc[1][r] + bias1[1];
      float gg = acc[2][r] + bias1[2];
      float go = acc[3][r] + bias1[3];
      float ii = sigf(gi), ff = sigf(gf), gt = tanh_fast(gg), oo = sigf(go);
      c1s[r] = ff*c1s[r] + ii*gt;
      float hn = oo * tanh_fast(c1s[r]);
      h1l[(hi4*4 + r)*LPH + w*16 + lo] = (_Float16)hn;
    }
    __syncthreads();
    #pragma unroll
    for (int kt = 0; kt < 2; ++kt)
      ah1[kt] = *(const half8*)&h1l[lo*LPH + kt*32 + hi4*8];
  }

  // ---- FC on h1(t=11) (already in ah1, all waves; wave 0 stores) ----
  if (w == 0){
    floatx4 a = {0.f,0.f,0.f,0.f};
    a = __builtin_amdgcn_mfma_f32_16x16x32_f16(ah1[0], FW[0], a, 0,0,0);
    a = __builtin_amdgcn_mfma_f32_16x16x32_f16(ah1[1], FW[1], a, 0,0,0);
    float bo = fcb[lo];
    #pragma unroll
    for (int r = 0; r < 4; ++r)
      out[(size_t)(nb + hi4*4 + r)*kOUT + lo] = a[r] + bo;
  }
}

extern "C" void kernel_launch(void* const* d_in, const int* in_sizes, int n_in,
                              void* d_out, int out_size, void* d_ws, size_t ws_size,
                              hipStream_t stream){
  const float* x    = (const float*)d_in[0];
  const int*   ei   = (const int*)  d_in[1];
  const float* gw0  = (const float*)d_in[2];
  const float* gb0  = (const float*)d_in[3];
  const float* gw1  = (const float*)d_in[4];
  const float* gb1  = (const float*)d_in[5];
  const float* wih0 = (const float*)d_in[6];
  const float* whh0 = (const float*)d_in[7];
  const float* bih0 = (const float*)d_in[8];
  const float* bhh0 = (const float*)d_in[9];
  const float* wih1 = (const float*)d_in[10];
  const float* whh1 = (const float*)d_in[11];
  const float* bih1 = (const float*)d_in[12];
  const float* bhh1 = (const float*)d_in[13];
  const float* fcw  = (const float*)d_in[14];
  const float* fcb  = (const float*)d_in[15];
  float* out = (float*)d_out;

  char* ws = (char*)d_ws;
  size_t p = 0;
  auto carve = [&](size_t bytes)->char*{
    char* r = ws + p;
    p += (bytes + 255) & ~(size_t)255;
    return r;
  };
  // anyf, cnt, cur contiguous -> single memset
  int*   anyf = (int*)  carve(256);
  int*   cnt  = (int*)  carve(sizeof(int)*kNN);
  int*   cur  = (int*)  carve(sizeof(int)*kNN);
  size_t zbytes = p;
  int*   offs = (int*)  carve(sizeof(int)*(kNN+1));
  float* dis  = (float*)carve(sizeof(float)*kNN);
  int2*  edat = (int2*) carve(sizeof(int2)*kNE);
  _Float16* xh   = (_Float16*)carve(sizeof(_Float16)*(size_t)kNN*kTT*kFIN); // 7.68MB
  _Float16* aggX = (_Float16*)carve(sizeof(_Float16)*(size_t)kNN*kTT*kFIN); // 7.68MB
  _Float16* bufA = (_Float16*)carve(sizeof(_Float16)*(size_t)kNN*kTT*kHH);  // 15.36MB
  _Float16* bufB = (_Float16*)carve(sizeof(_Float16)*(size_t)kNN*kTT*kHH);  // 15.36MB
  (void)ws_size; (void)in_sizes; (void)n_in; (void)out_size;

  hipMemsetAsync(ws, 0, zbytes, stream);
  k_detect_cast<<<120, 256, 0, stream>>>(ei, anyf, x, xh);
  k_deg    <<<(kNE+255)/256, 256, 0, stream>>>(ei, anyf, cnt);
  k_scan   <<<1, 256, 0, stream>>>(cnt, offs, dis);
  k_scatter<<<(kNE+255)/256, 256, 0, stream>>>(ei, anyf, offs, cur, dis, edat);

  // GCN-0: aggregate 32-feat x first (A_hat x), then GEMM (+gb0+relu), t-major
  k_agg<kFIN><<<(kNN*(kTT/4))/4, 256, 0, stream>>>(xh, aggX, dis, offs, edat);
  k_gemm<kFIN, kHH, false><<<(kNN*kTT)/64, 256, 0, stream>>>(aggX, gw0, gb0, bufB);
  // GCN-1: aggregate 64-feat, GEMM (+gb1+relu) writes node-major for LSTM
  k_agg<kHH><<<(kNN*(kTT/2))/4, 256, 0, stream>>>(bufB, bufA, dis, offs, edat);
  k_gemm<kHH, kHH, true><<<(kNN*kTT)/64, 256, 0, stream>>>(bufA, gw1, gb1, bufB);

  // Fused 2-layer LSTM + FC -> out (x LDS-staged; no global ops in t-loop)
  k_rec3<<<kNN/16, 256, 0, stream>>>(bufB, wih0, whh0, bih0, bhh0,
                                     wih1, whh1, bih1, bhh1, fcw, fcb, out);
}